// Round 1
// baseline (919.190 us; speedup 1.0000x reference)
//
#include <hip/hip_runtime.h>
#include <hip/hip_bf16.h>
#include <cstdint>

// Problem constants
// patch_tokens [8,1024,768] f32, vocab [30000,512] f32, W1 [512,768], gamma/beta [768],
// W2 [768,768], b2 [768]  ->  out [8,30000] f32 (softmax mixture weights)

#define CDIV(a,b) (((a)+(b)-1)/(b))

using bf16x8 = __attribute__((ext_vector_type(8))) __bf16;
using f32x4  = __attribute__((ext_vector_type(4))) float;

__device__ __forceinline__ unsigned short f2bf(float x) {
  unsigned u = __float_as_uint(x);
  u += 0x7fffu + ((u >> 16) & 1u);          // round-to-nearest-even
  return (unsigned short)(u >> 16);
}
__device__ __forceinline__ float bf2f(unsigned short b) {
  return __uint_as_float(((unsigned)b) << 16);
}
// order-preserving float<->uint key for atomicMax
__device__ __forceinline__ unsigned fkey(float x) {
  unsigned u = __float_as_uint(x);
  return (u & 0x80000000u) ? ~u : (u | 0x80000000u);
}
__device__ __forceinline__ float fdec(unsigned k) {
  unsigned u = (k & 0x80000000u) ? (k ^ 0x80000000u) : ~k;
  return __uint_as_float(u);
}

// ---------------------------------------------------------------------------
// NT GEMM: C[m][n] = sum_k A[m][k] * B[n][k], A:[M,K] bf16, B:[N,K] bf16.
// m97 structure: 128x128 tile, BK=32, 4 waves (each 64x64), global_load_lds w=16.
// EPI 0: store bf16 C (N=768)
// EPI 1: store bf16 (C + bias[n]) (N=768)
// EPI 2: per-column max over the 128 rows, atomicMax into maxkey[b*N + n],
//        b = m0/1024 (BM=128 divides 1024, so a block never straddles batches)
// ---------------------------------------------------------------------------
template<int EPI>
__global__ __launch_bounds__(256)
void gemm_nt_kernel(const unsigned short* __restrict__ A,
                    const unsigned short* __restrict__ B,
                    unsigned short* __restrict__ Cout,
                    const float* __restrict__ bias,
                    unsigned* __restrict__ maxkey,
                    int M, int N, int K)
{
  __shared__ __align__(16) unsigned short As[128 * 32];
  __shared__ __align__(16) unsigned short Bs[128 * 32];
  const int tid  = threadIdx.x;
  const int w    = tid >> 6, lane = tid & 63;
  const int m0   = blockIdx.y * 128, n0 = blockIdx.x * 128;
  const int wr   = w >> 1, wc = w & 1;
  const int lrow = lane & 15, kg = lane >> 4;

  f32x4 acc[4][4];
#pragma unroll
  for (int i = 0; i < 4; ++i)
#pragma unroll
    for (int j = 0; j < 4; ++j) acc[i][j] = f32x4{0.f, 0.f, 0.f, 0.f};

  for (int k0 = 0; k0 < K; k0 += 32) {
    // stage 8KB A-tile + 8KB B-tile; each wave issues 2 loads per tile (1KB each)
#pragma unroll
    for (int i = 0; i < 2; ++i) {
      const int li = w * 2 + i;          // 0..7, wave-uniform
      const int c  = li * 64 + lane;     // 16B chunk id, 512 per tile
      const int r  = c >> 2;             // tile row 0..127
      const int kc = (c & 3) * 8;        // k element offset 0/8/16/24
      {
        int row = m0 + r; if (row > M - 1) row = M - 1;
        const unsigned short* gp = A + (size_t)row * K + (k0 + kc);
        __builtin_amdgcn_global_load_lds(
            (const __attribute__((address_space(1))) void*)gp,
            (__attribute__((address_space(3))) void*)(As + li * 512), 16, 0, 0);
      }
      {
        int row = n0 + r; if (row > N - 1) row = N - 1;
        const unsigned short* gp = B + (size_t)row * K + (k0 + kc);
        __builtin_amdgcn_global_load_lds(
            (const __attribute__((address_space(1))) void*)gp,
            (__attribute__((address_space(3))) void*)(Bs + li * 512), 16, 0, 0);
      }
    }
    __syncthreads();   // compiler drains vmcnt before s_barrier

    bf16x8 af[4], bfr[4];
#pragma unroll
    for (int fm = 0; fm < 4; ++fm)
      af[fm] = *(const bf16x8*)(As + (wr * 64 + fm * 16 + lrow) * 32 + kg * 8);
#pragma unroll
    for (int fn = 0; fn < 4; ++fn)
      bfr[fn] = *(const bf16x8*)(Bs + (wc * 64 + fn * 16 + lrow) * 32 + kg * 8);

#pragma unroll
    for (int fm = 0; fm < 4; ++fm)
#pragma unroll
      for (int fn = 0; fn < 4; ++fn)
        acc[fm][fn] = __builtin_amdgcn_mfma_f32_16x16x32_bf16(
            af[fm], bfr[fn], acc[fm][fn], 0, 0, 0);
    __syncthreads();
  }

  if (EPI == 2) {
    const int b = m0 >> 10;
#pragma unroll
    for (int fn = 0; fn < 4; ++fn) {
      float mx = acc[0][fn][0];
#pragma unroll
      for (int fm = 0; fm < 4; ++fm)
#pragma unroll
        for (int j = 0; j < 4; ++j) mx = fmaxf(mx, acc[fm][fn][j]);
      // reduce across the 4 kg groups -> max over this wave's 64 rows
      mx = fmaxf(mx, __shfl_xor(mx, 16));
      mx = fmaxf(mx, __shfl_xor(mx, 32));
      const int gn = n0 + wc * 64 + fn * 16 + lrow;
      if (lane < 16 && gn < N)
        atomicMax(maxkey + (size_t)b * N + gn, fkey(mx));
    }
  } else {
#pragma unroll
    for (int fm = 0; fm < 4; ++fm) {
      const int gmb = m0 + wr * 64 + fm * 16 + kg * 4;
#pragma unroll
      for (int fn = 0; fn < 4; ++fn) {
        const int gn = n0 + wc * 64 + fn * 16 + lrow;
        const float bv = (EPI == 1) ? bias[gn] : 0.0f;
#pragma unroll
        for (int j = 0; j < 4; ++j) {
          const int gm = gmb + j;
          if (gm < M) Cout[(size_t)gm * N + gn] = f2bf(acc[fm][fn][j] + bv);
        }
      }
    }
  }
}

// ---------------------------------------------------------------------------
// Row L2-normalize: one block per row; input f32 or bf16, output bf16.
// ---------------------------------------------------------------------------
template<bool INBF>
__global__ __launch_bounds__(256)
void rownorm_kernel(const void* __restrict__ in, unsigned short* __restrict__ out,
                    int cols)
{
  __shared__ float red[4];
  const int row = blockIdx.x;
  const size_t base = (size_t)row * cols;
  const float* fin = (const float*)in;
  const unsigned short* bin = (const unsigned short*)in;

  float ss = 0.f;
  for (int ci = threadIdx.x; ci < cols; ci += 256) {
    float x = INBF ? bf2f(bin[base + ci]) : fin[base + ci];
    ss += x * x;
  }
#pragma unroll
  for (int m = 32; m; m >>= 1) ss += __shfl_xor(ss, m);
  if ((threadIdx.x & 63) == 0) red[threadIdx.x >> 6] = ss;
  __syncthreads();
  const float tot = red[0] + red[1] + red[2] + red[3];
  const float inv = 1.0f / fmaxf(sqrtf(tot), 1e-12f);
  for (int ci = threadIdx.x; ci < cols; ci += 256) {
    float x = INBF ? bf2f(bin[base + ci]) : fin[base + ci];
    out[base + ci] = f2bf(x * inv);
  }
}

// Transpose f32 [R][Cc] -> bf16 [Cc][R] (tiny matrices; coalesced reads)
__global__ __launch_bounds__(256)
void transpose_kernel(const float* __restrict__ in, unsigned short* __restrict__ out,
                      int R, int Cc)
{
  int i = blockIdx.x * 256 + threadIdx.x;
  if (i < R * Cc) {
    int r = i / Cc, c = i - r * Cc;
    out[(size_t)c * R + r] = f2bf(in[i]);
  }
}

// BN stats over V=30000 rows, 768 channels: sums[ch], sums[768+ch]=sum of squares
__global__ __launch_bounds__(256)
void bnstats_kernel(const unsigned short* __restrict__ h, float* __restrict__ sums)
{
  const int r0 = blockIdx.x * 250;
  const int c0 = threadIdx.x, c1 = threadIdx.x + 256, c2 = threadIdx.x + 512;
  float a0 = 0, a1 = 0, a2 = 0, q0 = 0, q1 = 0, q2 = 0;
  for (int r = r0; r < r0 + 250; ++r) {
    const size_t base = (size_t)r * 768;
    float x0 = bf2f(h[base + c0]); a0 += x0; q0 += x0 * x0;
    float x1 = bf2f(h[base + c1]); a1 += x1; q1 += x1 * x1;
    float x2 = bf2f(h[base + c2]); a2 += x2; q2 += x2 * x2;
  }
  atomicAdd(&sums[c0], a0); atomicAdd(&sums[768 + c0], q0);
  atomicAdd(&sums[c1], a1); atomicAdd(&sums[768 + c1], q1);
  atomicAdd(&sums[c2], a2); atomicAdd(&sums[768 + c2], q2);
}

// In-place BN(train, biased var) + ReLU on bf16 h [30000][768]
__global__ __launch_bounds__(256)
void bnapply_kernel(unsigned short* __restrict__ h, const float* __restrict__ sums,
                    const float* __restrict__ gamma, const float* __restrict__ beta)
{
  const float invV = 1.0f / 30000.0f;
  const size_t total = 30000ull * 768;
  for (size_t i = blockIdx.x * 256ull + threadIdx.x; i < total; i += 2048ull * 256) {
    const int ch = (int)(i % 768);
    const float mean = sums[ch] * invV;
    const float var  = sums[768 + ch] * invV - mean * mean;
    const float sc   = gamma[ch] / sqrtf(var + 1e-5f);
    const float y    = (bf2f(h[i]) - mean) * sc + beta[ch];
    h[i] = f2bf(fmaxf(y, 0.0f));
  }
}

// Softmax over V=30000 per batch row; logits decoded from max-key buffer; /T = *5
__global__ __launch_bounds__(1024)
void softmax_kernel(const unsigned* __restrict__ mk, float* __restrict__ out)
{
  __shared__ float red[16];
  const int b = blockIdx.x;
  const unsigned* row = mk + (size_t)b * 30000;
  const int tid = threadIdx.x;

  float m = -3.0e38f;
  for (int v = tid; v < 30000; v += 1024) m = fmaxf(m, fdec(row[v]));
#pragma unroll
  for (int s = 32; s; s >>= 1) m = fmaxf(m, __shfl_xor(m, s));
  if ((tid & 63) == 0) red[tid >> 6] = m;
  __syncthreads();
  float bm = red[0];
#pragma unroll
  for (int i = 1; i < 16; ++i) bm = fmaxf(bm, red[i]);
  __syncthreads();

  float s = 0.f;
  for (int v = tid; v < 30000; v += 1024) s += expf((fdec(row[v]) - bm) * 5.0f);
#pragma unroll
  for (int sh = 32; sh; sh >>= 1) s += __shfl_xor(s, sh);
  if ((tid & 63) == 0) red[tid >> 6] = s;
  __syncthreads();
  float bs = 0.f;
#pragma unroll
  for (int i = 0; i < 16; ++i) bs += red[i];

  for (int v = tid; v < 30000; v += 1024)
    out[(size_t)b * 30000 + v] = expf((fdec(row[v]) - bm) * 5.0f) / bs;
}

extern "C" void kernel_launch(void* const* d_in, const int* in_sizes, int n_in,
                              void* d_out, int out_size, void* d_ws, size_t ws_size,
                              hipStream_t stream)
{
  (void)in_sizes; (void)n_in; (void)out_size; (void)ws_size;
  const float* patch = (const float*)d_in[0];   // [8,1024,768]
  const float* vocab = (const float*)d_in[1];   // [30000,512]
  const float* W1    = (const float*)d_in[2];   // [512,768]
  const float* gamma = (const float*)d_in[3];   // [768]
  const float* beta  = (const float*)d_in[4];   // [768]
  const float* W2    = (const float*)d_in[5];   // [768,768]
  const float* b2    = (const float*)d_in[6];   // [768]
  float* out = (float*)d_out;                   // [8,30000]

  char* ws = (char*)d_ws;
  size_t off = 0;
  auto alloc = [&](size_t bytes) {
    char* p = ws + off;
    off += (bytes + 1023) & ~(size_t)1023;
    return p;
  };
  unsigned short* vocab_n = (unsigned short*)alloc(30000ull * 512 * 2);  // bf16
  unsigned short* pt_n    = (unsigned short*)alloc(8192ull * 768 * 2);   // bf16
  unsigned short* W1T     = (unsigned short*)alloc(768ull * 512 * 2);    // bf16 [768][512]
  unsigned short* W2T     = (unsigned short*)alloc(768ull * 768 * 2);    // bf16 [768][768]
  unsigned short* hbuf    = (unsigned short*)alloc(30000ull * 768 * 2);  // bf16
  unsigned short* pbuf    = (unsigned short*)alloc(30000ull * 768 * 2);  // bf16
  unsigned short* proto   = (unsigned short*)alloc(30000ull * 768 * 2);  // bf16
  float*          bnsums  = (float*)alloc(768ull * 2 * 4);
  unsigned*       maxkey  = (unsigned*)alloc(8ull * 30000 * 4);

  hipMemsetAsync(bnsums, 0, 768ull * 2 * 4, stream);
  hipMemsetAsync(maxkey, 0, 8ull * 30000 * 4, stream);   // key 0 == -inf

  transpose_kernel<<<CDIV(512 * 768, 256), 256, 0, stream>>>(W1, W1T, 512, 768);
  transpose_kernel<<<CDIV(768 * 768, 256), 256, 0, stream>>>(W2, W2T, 768, 768);
  rownorm_kernel<false><<<30000, 256, 0, stream>>>(vocab, vocab_n, 512);
  rownorm_kernel<false><<<8192, 256, 0, stream>>>(patch, pt_n, 768);

  // h = vocab_n @ W1  (NT with W1T), 30000x768, K=512
  gemm_nt_kernel<0><<<dim3(6, 235), 256, 0, stream>>>(
      vocab_n, W1T, hbuf, nullptr, nullptr, 30000, 768, 512);
  bnstats_kernel<<<120, 256, 0, stream>>>(hbuf, bnsums);
  bnapply_kernel<<<2048, 256, 0, stream>>>(hbuf, bnsums, gamma, beta);
  // p = h_bn @ W2 + b2 (NT with W2T), 30000x768, K=768
  gemm_nt_kernel<1><<<dim3(6, 235), 256, 0, stream>>>(
      hbuf, W2T, pbuf, b2, nullptr, 30000, 768, 768);
  rownorm_kernel<true><<<30000, 256, 0, stream>>>(pbuf, proto, 768);

  // logits fused with max over patches: [8192 x 30000], K=768 -> maxkey[8][30000]
  gemm_nt_kernel<2><<<dim3(235, 64), 256, 0, stream>>>(
      pt_n, proto, nullptr, nullptr, maxkey, 8192, 30000, 768);

  softmax_kernel<<<8, 1024, 0, stream>>>(maxkey, out);
}

// Round 2
// 734.983 us; speedup vs baseline: 1.2506x; 1.2506x over previous
//
#include <hip/hip_runtime.h>
#include <hip/hip_bf16.h>
#include <cstdint>

// patch_tokens [8,1024,768] f32, vocab [30000,512] f32, W1 [512,768], gamma/beta [768],
// W2 [768,768], b2 [768]  ->  out [8,30000] f32 (softmax mixture weights)

#define CDIV(a,b) (((a)+(b)-1)/(b))

using bf16x8 = __attribute__((ext_vector_type(8))) __bf16;
using f32x4  = __attribute__((ext_vector_type(4))) float;

__device__ __forceinline__ unsigned short f2bf(float x) {
  unsigned u = __float_as_uint(x);
  u += 0x7fffu + ((u >> 16) & 1u);          // round-to-nearest-even
  return (unsigned short)(u >> 16);
}
__device__ __forceinline__ float bf2f(unsigned short b) {
  return __uint_as_float(((unsigned)b) << 16);
}
// order-preserving float<->uint key for atomicMax
__device__ __forceinline__ unsigned fkey(float x) {
  unsigned u = __float_as_uint(x);
  return (u & 0x80000000u) ? ~u : (u | 0x80000000u);
}
__device__ __forceinline__ float fdec(unsigned k) {
  unsigned u = (k & 0x80000000u) ? (k ^ 0x80000000u) : ~k;
  return __uint_as_float(u);
}

// ---------------------------------------------------------------------------
// Big GEMM, 256x256 tile, 8-phase schedule (T1+T2+T3+T4+T5).
// C[m][n] = sum_k A[m][k]*B[n][k]; A=[8192][768] bf16, B=[30208][768] bf16.
// Epilogue: per-column max over the tile's 256 rows -> atomicMax maxkey[b][n].
// LDS: 8 regions x 16KB: region(slot s, mat, khalf) = [256 rows][32 bf16],
// XOR-swizzled (chunk ^= (row>>1)&3) via pre-swizzled global source.
// Pipeline: stage 1 half-tile per phase, stream 6 half-tiles ahead,
// s_waitcnt vmcnt(8) at the two k-half boundaries per tile (never 0).
// ---------------------------------------------------------------------------
__global__ __launch_bounds__(512, 1)
void gemm256_max_kernel(const unsigned short* __restrict__ A,
                        const unsigned short* __restrict__ B,
                        unsigned* __restrict__ maxkey)
{
  constexpr int K = 768, NT = 12, NXT = 118;  // K-tiles of 64; n-tiles
  __shared__ __align__(16) unsigned short lds[8 * 8192];  // 128 KiB

  const int tid = threadIdx.x;
  const int w = tid >> 6, lane = tid & 63;
  const int lr = lane & 15, kg = lane >> 4;
  const int wr = w >> 2, wc = w & 3;          // 2 x 4 wave grid

  // bijective XCD swizzle: 3776 blocks = 8 XCDs x 472
  const int bid = blockIdx.x;
  const int wg = (bid & 7) * 472 + (bid >> 3);
  const long m0 = (long)(wg / NXT) * 256;
  const long n0 = (long)(wg % NXT) * 256;

  // stage one half-tile region: (slot, k-tile tk, mat 0=A/1=B, khalf h)
  auto stage = [&](int slot, int tk, int mat, int h) {
    const unsigned short* src = mat ? B : A;
    const long row0 = mat ? n0 : m0;
    unsigned short* dst = lds + (((slot * 2) + mat) * 2 + h) * 8192;
#pragma unroll
    for (int ld = 0; ld < 2; ++ld) {
      const int lc  = ld * 512 + tid;               // 16B chunk id 0..1023
      const int row = lc >> 2;                      // 0..255
      const int qc  = (lc & 3) ^ ((row >> 1) & 3);  // inverse-swizzled source chunk
      const unsigned short* gp = src + (row0 + row) * K + tk * 64 + h * 32 + qc * 8;
      __builtin_amdgcn_global_load_lds(
          (const __attribute__((address_space(1))) void*)gp,
          (__attribute__((address_space(3))) void*)(dst + (ld * 512 + (w << 6)) * 8),
          16, 0, 0);
    }
  };
  // swizzled fragment reads
  auto rdA = [&](int s, int h, int fm) -> bf16x8 {
    const int row = wr * 128 + fm * 16 + lr;
    const int pc  = kg ^ ((row >> 1) & 3);
    return *(const bf16x8*)(lds + ((s * 2 + 0) * 2 + h) * 8192 + row * 32 + pc * 8);
  };
  auto rdB = [&](int s, int h, int fn) -> bf16x8 {
    const int row = wc * 64 + fn * 16 + lr;
    const int pc  = kg ^ ((row >> 1) & 3);
    return *(const bf16x8*)(lds + ((s * 2 + 1) * 2 + h) * 8192 + row * 32 + pc * 8);
  };

  f32x4 acc[8][4];
#pragma unroll
  for (int i = 0; i < 8; ++i)
#pragma unroll
    for (int j = 0; j < 4; ++j) acc[i][j] = f32x4{0.f, 0.f, 0.f, 0.f};

  // prologue: 6 half-tiles in stream order
  stage(0, 0, 0, 0); stage(0, 0, 1, 0); stage(0, 0, 0, 1);
  stage(0, 0, 1, 1); stage(1, 1, 0, 0); stage(1, 1, 1, 0);
  asm volatile("s_waitcnt vmcnt(8)" ::: "memory");
  __builtin_amdgcn_s_barrier();

  bf16x8 a[4], b[4];
  auto tile_body = [&](int t, int s) {
    const int t1c = (t + 1 < NT) ? t + 1 : NT - 1;   // clamped addresses,
    const int t2c = (t + 2 < NT) ? t + 2 : NT - 1;   // slots stay scheduled
    const int s1  = s ^ 1;

    // ---- P0: k-half 0, m-half 0 ----
#pragma unroll
    for (int i = 0; i < 4; ++i) a[i] = rdA(s, 0, i);
#pragma unroll
    for (int i = 0; i < 4; ++i) b[i] = rdB(s, 0, i);
    stage(s1, t1c, 0, 1);                            // (t+1).A.k1
    __builtin_amdgcn_s_barrier();
    asm volatile("s_waitcnt lgkmcnt(0)" ::: "memory");
    __builtin_amdgcn_sched_barrier(0);
    __builtin_amdgcn_s_setprio(1);
#pragma unroll
    for (int fm = 0; fm < 4; ++fm)
#pragma unroll
      for (int fn = 0; fn < 4; ++fn)
        acc[fm][fn] = __builtin_amdgcn_mfma_f32_16x16x32_bf16(a[fm], b[fn], acc[fm][fn], 0, 0, 0);
    __builtin_amdgcn_s_setprio(0);
    __builtin_amdgcn_sched_barrier(0);
    __builtin_amdgcn_s_barrier();

    // ---- P1: k-half 0, m-half 1 ----
#pragma unroll
    for (int i = 0; i < 4; ++i) a[i] = rdA(s, 0, 4 + i);
    stage(s1, t1c, 1, 1);                            // (t+1).B.k1
    __builtin_amdgcn_s_barrier();
    asm volatile("s_waitcnt lgkmcnt(0)" ::: "memory");
    __builtin_amdgcn_sched_barrier(0);
    __builtin_amdgcn_s_setprio(1);
#pragma unroll
    for (int fm = 0; fm < 4; ++fm)
#pragma unroll
      for (int fn = 0; fn < 4; ++fn)
        acc[4 + fm][fn] = __builtin_amdgcn_mfma_f32_16x16x32_bf16(a[fm], b[fn], acc[4 + fm][fn], 0, 0, 0);
    __builtin_amdgcn_s_setprio(0);
    asm volatile("s_waitcnt vmcnt(8)" ::: "memory");  // t.A.k1, t.B.k1 landed
    __builtin_amdgcn_sched_barrier(0);
    __builtin_amdgcn_s_barrier();

    // ---- P2: k-half 1, m-half 0 ----
#pragma unroll
    for (int i = 0; i < 4; ++i) a[i] = rdA(s, 1, i);
#pragma unroll
    for (int i = 0; i < 4; ++i) b[i] = rdB(s, 1, i);
    stage(s, t2c, 0, 0);                             // (t+2).A.k0 (k0 of s: reads done)
    __builtin_amdgcn_s_barrier();
    asm volatile("s_waitcnt lgkmcnt(0)" ::: "memory");
    __builtin_amdgcn_sched_barrier(0);
    __builtin_amdgcn_s_setprio(1);
#pragma unroll
    for (int fm = 0; fm < 4; ++fm)
#pragma unroll
      for (int fn = 0; fn < 4; ++fn)
        acc[fm][fn] = __builtin_amdgcn_mfma_f32_16x16x32_bf16(a[fm], b[fn], acc[fm][fn], 0, 0, 0);
    __builtin_amdgcn_s_setprio(0);
    __builtin_amdgcn_sched_barrier(0);
    __builtin_amdgcn_s_barrier();

    // ---- P3: k-half 1, m-half 1 ----
#pragma unroll
    for (int i = 0; i < 4; ++i) a[i] = rdA(s, 1, 4 + i);
    stage(s, t2c, 1, 0);                             // (t+2).B.k0
    __builtin_amdgcn_s_barrier();
    asm volatile("s_waitcnt lgkmcnt(0)" ::: "memory");
    __builtin_amdgcn_sched_barrier(0);
    __builtin_amdgcn_s_setprio(1);
#pragma unroll
    for (int fm = 0; fm < 4; ++fm)
#pragma unroll
      for (int fn = 0; fn < 4; ++fn)
        acc[4 + fm][fn] = __builtin_amdgcn_mfma_f32_16x16x32_bf16(a[fm], b[fn], acc[4 + fm][fn], 0, 0, 0);
    __builtin_amdgcn_s_setprio(0);
    asm volatile("s_waitcnt vmcnt(8)" ::: "memory");  // (t+1).A.k0, (t+1).B.k0 landed
    __builtin_amdgcn_sched_barrier(0);
    __builtin_amdgcn_s_barrier();
  };

  for (int tt = 0; tt < NT; tt += 2) { tile_body(tt, 0); tile_body(tt + 1, 1); }

  // epilogue: max over this wave's 128 rows per column, then atomicMax
  const int bb = (int)(m0 >> 10);   // 256 | 1024 so tile never straddles batches
#pragma unroll
  for (int fn = 0; fn < 4; ++fn) {
    float mx = acc[0][fn][0];
#pragma unroll
    for (int fm = 0; fm < 8; ++fm)
#pragma unroll
      for (int j = 0; j < 4; ++j) mx = fmaxf(mx, acc[fm][fn][j]);
    mx = fmaxf(mx, __shfl_xor(mx, 16));
    mx = fmaxf(mx, __shfl_xor(mx, 32));
    const long gn = n0 + wc * 64 + fn * 16 + lr;
    if (lane < 16)
      atomicMax(maxkey + (long)bb * 30208 + gn, fkey(mx));
  }
}

// ---------------------------------------------------------------------------
// 128x128 NT GEMM (m97 structure) for the two small GEMMs.
// EPI 0: store bf16 C; EPI 1: store bf16 (C + bias[n])
// ---------------------------------------------------------------------------
template<int EPI>
__global__ __launch_bounds__(256)
void gemm_nt_kernel(const unsigned short* __restrict__ A,
                    const unsigned short* __restrict__ B,
                    unsigned short* __restrict__ Cout,
                    const float* __restrict__ bias,
                    int M, int N, int K)
{
  __shared__ __align__(16) unsigned short As[128 * 32];
  __shared__ __align__(16) unsigned short Bs[128 * 32];
  const int tid  = threadIdx.x;
  const int w    = tid >> 6, lane = tid & 63;
  const int m0   = blockIdx.y * 128, n0 = blockIdx.x * 128;
  const int wr   = w >> 1, wc = w & 1;
  const int lrow = lane & 15, kg = lane >> 4;

  f32x4 acc[4][4];
#pragma unroll
  for (int i = 0; i < 4; ++i)
#pragma unroll
    for (int j = 0; j < 4; ++j) acc[i][j] = f32x4{0.f, 0.f, 0.f, 0.f};

  for (int k0 = 0; k0 < K; k0 += 32) {
#pragma unroll
    for (int i = 0; i < 2; ++i) {
      const int li = w * 2 + i;
      const int c  = li * 64 + lane;
      const int r  = c >> 2;
      const int kc = (c & 3) * 8;
      {
        int row = m0 + r; if (row > M - 1) row = M - 1;
        const unsigned short* gp = A + (size_t)row * K + (k0 + kc);
        __builtin_amdgcn_global_load_lds(
            (const __attribute__((address_space(1))) void*)gp,
            (__attribute__((address_space(3))) void*)(As + li * 512), 16, 0, 0);
      }
      {
        int row = n0 + r; if (row > N - 1) row = N - 1;
        const unsigned short* gp = B + (size_t)row * K + (k0 + kc);
        __builtin_amdgcn_global_load_lds(
            (const __attribute__((address_space(1))) void*)gp,
            (__attribute__((address_space(3))) void*)(Bs + li * 512), 16, 0, 0);
      }
    }
    __syncthreads();

    bf16x8 af[4], bfr[4];
#pragma unroll
    for (int fm = 0; fm < 4; ++fm)
      af[fm] = *(const bf16x8*)(As + (wr * 64 + fm * 16 + lrow) * 32 + kg * 8);
#pragma unroll
    for (int fn = 0; fn < 4; ++fn)
      bfr[fn] = *(const bf16x8*)(Bs + (wc * 64 + fn * 16 + lrow) * 32 + kg * 8);

#pragma unroll
    for (int fm = 0; fm < 4; ++fm)
#pragma unroll
      for (int fn = 0; fn < 4; ++fn)
        acc[fm][fn] = __builtin_amdgcn_mfma_f32_16x16x32_bf16(
            af[fm], bfr[fn], acc[fm][fn], 0, 0, 0);
    __syncthreads();
  }

#pragma unroll
  for (int fm = 0; fm < 4; ++fm) {
    const int gmb = m0 + wr * 64 + fm * 16 + kg * 4;
#pragma unroll
    for (int fn = 0; fn < 4; ++fn) {
      const int gn = n0 + wc * 64 + fn * 16 + lrow;
      const float bv = (EPI == 1) ? bias[gn] : 0.0f;
#pragma unroll
      for (int j = 0; j < 4; ++j) {
        const int gm = gmb + j;
        if (gm < M) Cout[(size_t)gm * N + gn] = f2bf(acc[fm][fn][j] + bv);
      }
    }
  }
}

// ---------------------------------------------------------------------------
template<bool INBF>
__global__ __launch_bounds__(256)
void rownorm_kernel(const void* __restrict__ in, unsigned short* __restrict__ out,
                    int cols)
{
  __shared__ float red[4];
  const int row = blockIdx.x;
  const size_t base = (size_t)row * cols;
  const float* fin = (const float*)in;
  const unsigned short* bin = (const unsigned short*)in;

  float ss = 0.f;
  for (int ci = threadIdx.x; ci < cols; ci += 256) {
    float x = INBF ? bf2f(bin[base + ci]) : fin[base + ci];
    ss += x * x;
  }
#pragma unroll
  for (int m = 32; m; m >>= 1) ss += __shfl_xor(ss, m);
  if ((threadIdx.x & 63) == 0) red[threadIdx.x >> 6] = ss;
  __syncthreads();
  const float tot = red[0] + red[1] + red[2] + red[3];
  const float inv = 1.0f / fmaxf(sqrtf(tot), 1e-12f);
  for (int ci = threadIdx.x; ci < cols; ci += 256) {
    float x = INBF ? bf2f(bin[base + ci]) : fin[base + ci];
    out[base + ci] = f2bf(x * inv);
  }
}

__global__ __launch_bounds__(256)
void transpose_kernel(const float* __restrict__ in, unsigned short* __restrict__ out,
                      int R, int Cc)
{
  int i = blockIdx.x * 256 + threadIdx.x;
  if (i < R * Cc) {
    int r = i / Cc, c = i - r * Cc;
    out[(size_t)c * R + r] = f2bf(in[i]);
  }
}

__global__ __launch_bounds__(256)
void bnstats_kernel(const unsigned short* __restrict__ h, float* __restrict__ sums)
{
  const int r0 = blockIdx.x * 250;
  const int c0 = threadIdx.x, c1 = threadIdx.x + 256, c2 = threadIdx.x + 512;
  float a0 = 0, a1 = 0, a2 = 0, q0 = 0, q1 = 0, q2 = 0;
  for (int r = r0; r < r0 + 250; ++r) {
    const size_t base = (size_t)r * 768;
    float x0 = bf2f(h[base + c0]); a0 += x0; q0 += x0 * x0;
    float x1 = bf2f(h[base + c1]); a1 += x1; q1 += x1 * x1;
    float x2 = bf2f(h[base + c2]); a2 += x2; q2 += x2 * x2;
  }
  atomicAdd(&sums[c0], a0); atomicAdd(&sums[768 + c0], q0);
  atomicAdd(&sums[c1], a1); atomicAdd(&sums[768 + c1], q1);
  atomicAdd(&sums[c2], a2); atomicAdd(&sums[768 + c2], q2);
}

__global__ __launch_bounds__(256)
void bnapply_kernel(unsigned short* __restrict__ h, const float* __restrict__ sums,
                    const float* __restrict__ gamma, const float* __restrict__ beta)
{
  const float invV = 1.0f / 30000.0f;
  const size_t total = 30000ull * 768;
  for (size_t i = blockIdx.x * 256ull + threadIdx.x; i < total; i += 2048ull * 256) {
    const int ch = (int)(i % 768);
    const float mean = sums[ch] * invV;
    const float var  = sums[768 + ch] * invV - mean * mean;
    const float sc   = gamma[ch] / sqrtf(var + 1e-5f);
    const float y    = (bf2f(h[i]) - mean) * sc + beta[ch];
    h[i] = f2bf(fmaxf(y, 0.0f));
  }
}

__global__ __launch_bounds__(1024)
void softmax_kernel(const unsigned* __restrict__ mk, float* __restrict__ out)
{
  __shared__ float red[16];
  const int b = blockIdx.x;
  const unsigned* row = mk + (size_t)b * 30208;
  const int tid = threadIdx.x;

  float m = -3.0e38f;
  for (int v = tid; v < 30000; v += 1024) m = fmaxf(m, fdec(row[v]));
#pragma unroll
  for (int s = 32; s; s >>= 1) m = fmaxf(m, __shfl_xor(m, s));
  if ((tid & 63) == 0) red[tid >> 6] = m;
  __syncthreads();
  float bm = red[0];
#pragma unroll
  for (int i = 1; i < 16; ++i) bm = fmaxf(bm, red[i]);
  __syncthreads();

  float s = 0.f;
  for (int v = tid; v < 30000; v += 1024) s += expf((fdec(row[v]) - bm) * 5.0f);
#pragma unroll
  for (int sh = 32; sh; sh >>= 1) s += __shfl_xor(s, sh);
  if ((tid & 63) == 0) red[tid >> 6] = s;
  __syncthreads();
  float bs = 0.f;
#pragma unroll
  for (int i = 0; i < 16; ++i) bs += red[i];

  for (int v = tid; v < 30000; v += 1024)
    out[(size_t)b * 30000 + v] = expf((fdec(row[v]) - bm) * 5.0f) / bs;
}

extern "C" void kernel_launch(void* const* d_in, const int* in_sizes, int n_in,
                              void* d_out, int out_size, void* d_ws, size_t ws_size,
                              hipStream_t stream)
{
  (void)in_sizes; (void)n_in; (void)out_size; (void)ws_size;
  const float* patch = (const float*)d_in[0];   // [8,1024,768]
  const float* vocab = (const float*)d_in[1];   // [30000,512]
  const float* W1    = (const float*)d_in[2];   // [512,768]
  const float* gamma = (const float*)d_in[3];   // [768]
  const float* beta  = (const float*)d_in[4];   // [768]
  const float* W2    = (const float*)d_in[5];   // [768,768]
  const float* b2    = (const float*)d_in[6];   // [768]
  float* out = (float*)d_out;                   // [8,30000]

  char* ws = (char*)d_ws;
  size_t off = 0;
  auto alloc = [&](size_t bytes) {
    char* p = ws + off;
    off += (bytes + 1023) & ~(size_t)1023;
    return p;
  };
  unsigned short* vocab_n = (unsigned short*)alloc(30000ull * 512 * 2);
  unsigned short* pt_n    = (unsigned short*)alloc(8192ull * 768 * 2);
  unsigned short* W1T     = (unsigned short*)alloc(768ull * 512 * 2);
  unsigned short* W2T     = (unsigned short*)alloc(768ull * 768 * 2);
  unsigned short* hbuf    = (unsigned short*)alloc(30000ull * 768 * 2);
  unsigned short* pbuf    = (unsigned short*)alloc(30000ull * 768 * 2);
  unsigned short* proto   = (unsigned short*)alloc(30208ull * 768 * 2);  // padded V
  float*          bnsums  = (float*)alloc(768ull * 2 * 4);
  unsigned*       maxkey  = (unsigned*)alloc(8ull * 30208 * 4);

  hipMemsetAsync(bnsums, 0, 768ull * 2 * 4, stream);
  hipMemsetAsync(maxkey, 0, 8ull * 30208 * 4, stream);              // key 0 decodes below any real max
  hipMemsetAsync(proto + 30000ull * 768, 0, 208ull * 768 * 2, stream);  // zero pad rows

  transpose_kernel<<<CDIV(512 * 768, 256), 256, 0, stream>>>(W1, W1T, 512, 768);
  transpose_kernel<<<CDIV(768 * 768, 256), 256, 0, stream>>>(W2, W2T, 768, 768);
  rownorm_kernel<false><<<30000, 256, 0, stream>>>(vocab, vocab_n, 512);
  rownorm_kernel<false><<<8192, 256, 0, stream>>>(patch, pt_n, 768);

  gemm_nt_kernel<0><<<dim3(6, 235), 256, 0, stream>>>(
      vocab_n, W1T, hbuf, nullptr, 30000, 768, 512);
  bnstats_kernel<<<120, 256, 0, stream>>>(hbuf, bnsums);
  bnapply_kernel<<<2048, 256, 0, stream>>>(hbuf, bnsums, gamma, beta);
  gemm_nt_kernel<1><<<dim3(6, 235), 256, 0, stream>>>(
      hbuf, W2T, pbuf, b2, 30000, 768, 768);
  rownorm_kernel<true><<<30000, 256, 0, stream>>>(pbuf, proto, 768);

  // big fused GEMM + max: 3776 blocks of 512 threads
  gemm256_max_kernel<<<3776, 512, 0, stream>>>(pt_n, proto, maxkey);

  softmax_kernel<<<8, 1024, 0, stream>>>(maxkey, out);
}

// Round 3
// 635.428 us; speedup vs baseline: 1.4466x; 1.1567x over previous
//
#include <hip/hip_runtime.h>
#include <hip/hip_bf16.h>
#include <cstdint>

// patch_tokens [8,1024,768] f32, vocab [30000,512] f32, W1 [512,768], gamma/beta [768],
// W2 [768,768], b2 [768]  ->  out [8,30000] f32 (softmax mixture weights)

#define CDIV(a,b) (((a)+(b)-1)/(b))

using bf16x8 = __attribute__((ext_vector_type(8))) __bf16;
using f32x4  = __attribute__((ext_vector_type(4))) float;
using u16x8  = __attribute__((ext_vector_type(8))) unsigned short;
using u16x4  = __attribute__((ext_vector_type(4))) unsigned short;
using u32x4  = __attribute__((ext_vector_type(4))) unsigned;

__device__ __forceinline__ unsigned short f2bf(float x) {
  unsigned u = __float_as_uint(x);
  u += 0x7fffu + ((u >> 16) & 1u);          // round-to-nearest-even
  return (unsigned short)(u >> 16);
}
__device__ __forceinline__ float bf2f(unsigned short b) {
  return __uint_as_float(((unsigned)b) << 16);
}
// order-preserving float<->uint key for atomicMax
__device__ __forceinline__ unsigned fkey(float x) {
  unsigned u = __float_as_uint(x);
  return (u & 0x80000000u) ? ~u : (u | 0x80000000u);
}
__device__ __forceinline__ float fdec(unsigned k) {
  unsigned u = (k & 0x80000000u) ? (k ^ 0x80000000u) : ~k;
  return __uint_as_float(u);
}

// ---------------------------------------------------------------------------
// Big GEMM, 256x256 tile, 8-phase schedule (T1+T2+T3+T4+T5). Unchanged from R2:
// MfmaUtil 48%, bank conflicts 0, 365us.
// ---------------------------------------------------------------------------
__global__ __launch_bounds__(512, 1)
void gemm256_max_kernel(const unsigned short* __restrict__ A,
                        const unsigned short* __restrict__ B,
                        unsigned* __restrict__ maxkey)
{
  constexpr int K = 768, NT = 12, NXT = 118;
  __shared__ __align__(16) unsigned short lds[8 * 8192];  // 128 KiB

  const int tid = threadIdx.x;
  const int w = tid >> 6, lane = tid & 63;
  const int lr = lane & 15, kg = lane >> 4;
  const int wr = w >> 2, wc = w & 3;

  const int bid = blockIdx.x;
  const int wg = (bid & 7) * 472 + (bid >> 3);   // bijective: 3776 = 8*472
  const long m0 = (long)(wg / NXT) * 256;
  const long n0 = (long)(wg % NXT) * 256;

  auto stage = [&](int slot, int tk, int mat, int h) {
    const unsigned short* src = mat ? B : A;
    const long row0 = mat ? n0 : m0;
    unsigned short* dst = lds + (((slot * 2) + mat) * 2 + h) * 8192;
#pragma unroll
    for (int ld = 0; ld < 2; ++ld) {
      const int lc  = ld * 512 + tid;
      const int row = lc >> 2;
      const int qc  = (lc & 3) ^ ((row >> 1) & 3);
      const unsigned short* gp = src + (row0 + row) * K + tk * 64 + h * 32 + qc * 8;
      __builtin_amdgcn_global_load_lds(
          (const __attribute__((address_space(1))) void*)gp,
          (__attribute__((address_space(3))) void*)(dst + (ld * 512 + (w << 6)) * 8),
          16, 0, 0);
    }
  };
  auto rdA = [&](int s, int h, int fm) -> bf16x8 {
    const int row = wr * 128 + fm * 16 + lr;
    const int pc  = kg ^ ((row >> 1) & 3);
    return *(const bf16x8*)(lds + ((s * 2 + 0) * 2 + h) * 8192 + row * 32 + pc * 8);
  };
  auto rdB = [&](int s, int h, int fn) -> bf16x8 {
    const int row = wc * 64 + fn * 16 + lr;
    const int pc  = kg ^ ((row >> 1) & 3);
    return *(const bf16x8*)(lds + ((s * 2 + 1) * 2 + h) * 8192 + row * 32 + pc * 8);
  };

  f32x4 acc[8][4];
#pragma unroll
  for (int i = 0; i < 8; ++i)
#pragma unroll
    for (int j = 0; j < 4; ++j) acc[i][j] = f32x4{0.f, 0.f, 0.f, 0.f};

  stage(0, 0, 0, 0); stage(0, 0, 1, 0); stage(0, 0, 0, 1);
  stage(0, 0, 1, 1); stage(1, 1, 0, 0); stage(1, 1, 1, 0);
  asm volatile("s_waitcnt vmcnt(8)" ::: "memory");
  __builtin_amdgcn_s_barrier();

  bf16x8 a[4], b[4];
  auto tile_body = [&](int t, int s) {
    const int t1c = (t + 1 < NT) ? t + 1 : NT - 1;
    const int t2c = (t + 2 < NT) ? t + 2 : NT - 1;
    const int s1  = s ^ 1;

    // ---- P0 ----
#pragma unroll
    for (int i = 0; i < 4; ++i) a[i] = rdA(s, 0, i);
#pragma unroll
    for (int i = 0; i < 4; ++i) b[i] = rdB(s, 0, i);
    stage(s1, t1c, 0, 1);
    __builtin_amdgcn_s_barrier();
    asm volatile("s_waitcnt lgkmcnt(0)" ::: "memory");
    __builtin_amdgcn_sched_barrier(0);
    __builtin_amdgcn_s_setprio(1);
#pragma unroll
    for (int fm = 0; fm < 4; ++fm)
#pragma unroll
      for (int fn = 0; fn < 4; ++fn)
        acc[fm][fn] = __builtin_amdgcn_mfma_f32_16x16x32_bf16(a[fm], b[fn], acc[fm][fn], 0, 0, 0);
    __builtin_amdgcn_s_setprio(0);
    __builtin_amdgcn_sched_barrier(0);
    __builtin_amdgcn_s_barrier();

    // ---- P1 ----
#pragma unroll
    for (int i = 0; i < 4; ++i) a[i] = rdA(s, 0, 4 + i);
    stage(s1, t1c, 1, 1);
    __builtin_amdgcn_s_barrier();
    asm volatile("s_waitcnt lgkmcnt(0)" ::: "memory");
    __builtin_amdgcn_sched_barrier(0);
    __builtin_amdgcn_s_setprio(1);
#pragma unroll
    for (int fm = 0; fm < 4; ++fm)
#pragma unroll
      for (int fn = 0; fn < 4; ++fn)
        acc[4 + fm][fn] = __builtin_amdgcn_mfma_f32_16x16x32_bf16(a[fm], b[fn], acc[4 + fm][fn], 0, 0, 0);
    __builtin_amdgcn_s_setprio(0);
    asm volatile("s_waitcnt vmcnt(8)" ::: "memory");
    __builtin_amdgcn_sched_barrier(0);
    __builtin_amdgcn_s_barrier();

    // ---- P2 ----
#pragma unroll
    for (int i = 0; i < 4; ++i) a[i] = rdA(s, 1, i);
#pragma unroll
    for (int i = 0; i < 4; ++i) b[i] = rdB(s, 1, i);
    stage(s, t2c, 0, 0);
    __builtin_amdgcn_s_barrier();
    asm volatile("s_waitcnt lgkmcnt(0)" ::: "memory");
    __builtin_amdgcn_sched_barrier(0);
    __builtin_amdgcn_s_setprio(1);
#pragma unroll
    for (int fm = 0; fm < 4; ++fm)
#pragma unroll
      for (int fn = 0; fn < 4; ++fn)
        acc[fm][fn] = __builtin_amdgcn_mfma_f32_16x16x32_bf16(a[fm], b[fn], acc[fm][fn], 0, 0, 0);
    __builtin_amdgcn_s_setprio(0);
    __builtin_amdgcn_sched_barrier(0);
    __builtin_amdgcn_s_barrier();

    // ---- P3 ----
#pragma unroll
    for (int i = 0; i < 4; ++i) a[i] = rdA(s, 1, 4 + i);
    stage(s, t2c, 1, 0);
    __builtin_amdgcn_s_barrier();
    asm volatile("s_waitcnt lgkmcnt(0)" ::: "memory");
    __builtin_amdgcn_sched_barrier(0);
    __builtin_amdgcn_s_setprio(1);
#pragma unroll
    for (int fm = 0; fm < 4; ++fm)
#pragma unroll
      for (int fn = 0; fn < 4; ++fn)
        acc[4 + fm][fn] = __builtin_amdgcn_mfma_f32_16x16x32_bf16(a[fm], b[fn], acc[4 + fm][fn], 0, 0, 0);
    __builtin_amdgcn_s_setprio(0);
    asm volatile("s_waitcnt vmcnt(8)" ::: "memory");
    __builtin_amdgcn_sched_barrier(0);
    __builtin_amdgcn_s_barrier();
  };

  for (int tt = 0; tt < NT; tt += 2) { tile_body(tt, 0); tile_body(tt + 1, 1); }

  const int bb = (int)(m0 >> 10);
#pragma unroll
  for (int fn = 0; fn < 4; ++fn) {
    float mx = acc[0][fn][0];
#pragma unroll
    for (int fm = 0; fm < 8; ++fm)
#pragma unroll
      for (int j = 0; j < 4; ++j) mx = fmaxf(mx, acc[fm][fn][j]);
    mx = fmaxf(mx, __shfl_xor(mx, 16));
    mx = fmaxf(mx, __shfl_xor(mx, 32));
    const long gn = n0 + wc * 64 + fn * 16 + lr;
    if (lane < 16)
      atomicMax(maxkey + (long)bb * 30208 + gn, fkey(mx));
  }
}

// ---------------------------------------------------------------------------
// 128x128 NT GEMM (m97 structure). EPI 0: store bf16 C; EPI 1: +bias.
// STATS: fuse per-column sum/sumsq (BN statistics) from f32 acc.
// ---------------------------------------------------------------------------
template<int EPI, bool STATS>
__global__ __launch_bounds__(256)
void gemm_nt_kernel(const unsigned short* __restrict__ A,
                    const unsigned short* __restrict__ B,
                    unsigned short* __restrict__ Cout,
                    const float* __restrict__ bias,
                    float* __restrict__ sums,
                    int M, int N, int K)
{
  __shared__ __align__(16) unsigned short As[128 * 32];
  __shared__ __align__(16) unsigned short Bs[128 * 32];
  const int tid  = threadIdx.x;
  const int w    = tid >> 6, lane = tid & 63;
  const int m0   = blockIdx.y * 128, n0 = blockIdx.x * 128;
  const int wr   = w >> 1, wc = w & 1;
  const int lrow = lane & 15, kg = lane >> 4;

  f32x4 acc[4][4];
#pragma unroll
  for (int i = 0; i < 4; ++i)
#pragma unroll
    for (int j = 0; j < 4; ++j) acc[i][j] = f32x4{0.f, 0.f, 0.f, 0.f};

  for (int k0 = 0; k0 < K; k0 += 32) {
#pragma unroll
    for (int i = 0; i < 2; ++i) {
      const int li = w * 2 + i;
      const int c  = li * 64 + lane;
      const int r  = c >> 2;
      const int kc = (c & 3) * 8;
      {
        int row = m0 + r; if (row > M - 1) row = M - 1;
        const unsigned short* gp = A + (size_t)row * K + (k0 + kc);
        __builtin_amdgcn_global_load_lds(
            (const __attribute__((address_space(1))) void*)gp,
            (__attribute__((address_space(3))) void*)(As + li * 512), 16, 0, 0);
      }
      {
        int row = n0 + r; if (row > N - 1) row = N - 1;
        const unsigned short* gp = B + (size_t)row * K + (k0 + kc);
        __builtin_amdgcn_global_load_lds(
            (const __attribute__((address_space(1))) void*)gp,
            (__attribute__((address_space(3))) void*)(Bs + li * 512), 16, 0, 0);
      }
    }
    __syncthreads();

    bf16x8 af[4], bfr[4];
#pragma unroll
    for (int fm = 0; fm < 4; ++fm)
      af[fm] = *(const bf16x8*)(As + (wr * 64 + fm * 16 + lrow) * 32 + kg * 8);
#pragma unroll
    for (int fn = 0; fn < 4; ++fn)
      bfr[fn] = *(const bf16x8*)(Bs + (wc * 64 + fn * 16 + lrow) * 32 + kg * 8);

#pragma unroll
    for (int fm = 0; fm < 4; ++fm)
#pragma unroll
      for (int fn = 0; fn < 4; ++fn)
        acc[fm][fn] = __builtin_amdgcn_mfma_f32_16x16x32_bf16(
            af[fm], bfr[fn], acc[fm][fn], 0, 0, 0);
    __syncthreads();
  }

#pragma unroll
  for (int fm = 0; fm < 4; ++fm) {
    const int gmb = m0 + wr * 64 + fm * 16 + kg * 4;
#pragma unroll
    for (int fn = 0; fn < 4; ++fn) {
      const int gn = n0 + wc * 64 + fn * 16 + lrow;
      const float bv = (EPI == 1) ? bias[gn] : 0.0f;
#pragma unroll
      for (int j = 0; j < 4; ++j) {
        const int gm = gmb + j;
        if (gm < M) Cout[(size_t)gm * N + gn] = f2bf(acc[fm][fn][j] + bv);
      }
    }
  }

  if (STATS) {
    // per-column sum / sumsq over this wave's 64 rows, then atomicAdd
#pragma unroll
    for (int fn = 0; fn < 4; ++fn) {
      const int gn = n0 + wc * 64 + fn * 16 + lrow;
      float s = 0.f, q = 0.f;
#pragma unroll
      for (int fm = 0; fm < 4; ++fm) {
        const int gmb = m0 + wr * 64 + fm * 16 + kg * 4;
#pragma unroll
        for (int j = 0; j < 4; ++j) {
          if (gmb + j < M) {
            const float x = acc[fm][fn][j];
            s += x; q += x * x;
          }
        }
      }
      s += __shfl_xor(s, 16); s += __shfl_xor(s, 32);
      q += __shfl_xor(q, 16); q += __shfl_xor(q, 32);
      if (lane < 16 && gn < N) {
        atomicAdd(sums + gn, s);
        atomicAdd(sums + 768 + gn, q);
      }
    }
  }
}

// ---------------------------------------------------------------------------
// Row L2-normalize, fully vectorized: one vector chunk per thread (cols/VE <= BLOCK).
// ---------------------------------------------------------------------------
template<int BLOCK, bool INBF>
__global__ __launch_bounds__(BLOCK)
void rownorm_kernel(const void* __restrict__ in, unsigned short* __restrict__ out,
                    int cols)
{
  __shared__ float red[BLOCK / 64];
  constexpr int VE = INBF ? 8 : 4;
  const int row = blockIdx.x, tid = threadIdx.x;
  const int nch = cols / VE;

  float x[VE];
  float ss = 0.f;
  if (tid < nch) {
    if (INBF) {
      const u16x8 v = ((const u16x8*)((const unsigned short*)in + (size_t)row * cols))[tid];
#pragma unroll
      for (int j = 0; j < 8; ++j) { x[j] = bf2f(v[j]); ss += x[j] * x[j]; }
    } else {
      const f32x4 v = ((const f32x4*)((const float*)in + (size_t)row * cols))[tid];
#pragma unroll
      for (int j = 0; j < 4; ++j) { x[j] = v[j]; ss += x[j] * x[j]; }
    }
  }
#pragma unroll
  for (int m = 32; m; m >>= 1) ss += __shfl_xor(ss, m);
  if ((tid & 63) == 0) red[tid >> 6] = ss;
  __syncthreads();
  float tot = 0.f;
#pragma unroll
  for (int i = 0; i < BLOCK / 64; ++i) tot += red[i];
  const float inv = 1.0f / fmaxf(sqrtf(tot), 1e-12f);

  if (tid < nch) {
    if (INBF) {
      u16x8 o;
#pragma unroll
      for (int j = 0; j < 8; ++j) o[j] = f2bf(x[j] * inv);
      ((u16x8*)(out + (size_t)row * cols))[tid] = o;
    } else {
      u16x4 o;
#pragma unroll
      for (int j = 0; j < 4; ++j) o[j] = f2bf(x[j] * inv);
      ((u16x4*)(out + (size_t)row * cols))[tid] = o;
    }
  }
}

// Transpose f32 [R][Cc] -> bf16 [Cc][R]
__global__ __launch_bounds__(256)
void transpose_kernel(const float* __restrict__ in, unsigned short* __restrict__ out,
                      int R, int Cc)
{
  int i = blockIdx.x * 256 + threadIdx.x;
  if (i < R * Cc) {
    int r = i / Cc, c = i - r * Cc;
    out[(size_t)c * R + r] = f2bf(in[i]);
  }
}

// scale/shift from accumulated sums: scale=gamma/sqrt(var+eps), shift=beta-mean*scale
__global__ __launch_bounds__(256)
void bnfinal_kernel(const float* __restrict__ sums, const float* __restrict__ gamma,
                    const float* __restrict__ beta, float* __restrict__ sc,
                    float* __restrict__ sh)
{
  const int ch = blockIdx.x * 256 + threadIdx.x;
  if (ch < 768) {
    const float invV = 1.0f / 30000.0f;
    const float mean = sums[ch] * invV;
    const float var  = sums[768 + ch] * invV - mean * mean;
    const float s    = gamma[ch] / sqrtf(var + 1e-5f);
    sc[ch] = s;
    sh[ch] = beta[ch] - mean * s;
  }
}

// In-place BN + ReLU, short8-vectorized. 30000*96 chunks of 8 bf16.
__global__ __launch_bounds__(256)
void bnapply_kernel(unsigned short* __restrict__ h, const float* __restrict__ sc,
                    const float* __restrict__ sh)
{
  const int total = 30000 * 96;
  for (int c = blockIdx.x * 256 + threadIdx.x; c < total; c += 2048 * 256) {
    const int ch = (c % 96) * 8;
    const u16x8 v = ((const u16x8*)h)[c];
    u16x8 o;
#pragma unroll
    for (int j = 0; j < 8; ++j) {
      const float y = fmaf(bf2f(v[j]), sc[ch + j], sh[ch + j]);
      o[j] = f2bf(fmaxf(y, 0.0f));
    }
    ((u16x8*)h)[c] = o;
  }
}

// Softmax with fixed shift: logits are dots of unit vectors => l in [-1,1].
// S = exp((l-1)*5) in [e^-10, 1]: no overflow, softmax shift-invariant.
__global__ __launch_bounds__(256)
void smpart_kernel(const unsigned* __restrict__ mk, float* __restrict__ partsum)
{
  __shared__ float red[4];
  const int b = blockIdx.y;
  const unsigned* row = mk + (size_t)b * 30208 + blockIdx.x * 1000;
  float s = 0.f;
  for (int t = threadIdx.x; t < 1000; t += 256)
    s += expf((fdec(row[t]) - 1.0f) * 5.0f);
#pragma unroll
  for (int m = 32; m; m >>= 1) s += __shfl_xor(s, m);
  if ((threadIdx.x & 63) == 0) red[threadIdx.x >> 6] = s;
  __syncthreads();
  if (threadIdx.x == 0)
    atomicAdd(partsum + b, red[0] + red[1] + red[2] + red[3]);
}

__global__ __launch_bounds__(256)
void smfinal_kernel(const unsigned* __restrict__ mk, const float* __restrict__ partsum,
                    float* __restrict__ out)
{
  const int b = blockIdx.y;
  const int c = blockIdx.x * 256 + threadIdx.x;   // chunk of 8
  if (c < 3750) {
    const unsigned* row = mk + (size_t)b * 30208 + c * 8;
    const float inv = 1.0f / partsum[b];
    const u32x4 k0 = *(const u32x4*)row;
    const u32x4 k1 = *(const u32x4*)(row + 4);
    f32x4 o0, o1;
#pragma unroll
    for (int j = 0; j < 4; ++j) {
      o0[j] = expf((fdec(k0[j]) - 1.0f) * 5.0f) * inv;
      o1[j] = expf((fdec(k1[j]) - 1.0f) * 5.0f) * inv;
    }
    float* op = out + (size_t)b * 30000 + c * 8;
    *(f32x4*)op = o0;
    *(f32x4*)(op + 4) = o1;
  }
}

extern "C" void kernel_launch(void* const* d_in, const int* in_sizes, int n_in,
                              void* d_out, int out_size, void* d_ws, size_t ws_size,
                              hipStream_t stream)
{
  (void)in_sizes; (void)n_in; (void)out_size; (void)ws_size;
  const float* patch = (const float*)d_in[0];   // [8,1024,768]
  const float* vocab = (const float*)d_in[1];   // [30000,512]
  const float* W1    = (const float*)d_in[2];   // [512,768]
  const float* gamma = (const float*)d_in[3];   // [768]
  const float* beta  = (const float*)d_in[4];   // [768]
  const float* W2    = (const float*)d_in[5];   // [768,768]
  const float* b2    = (const float*)d_in[6];   // [768]
  float* out = (float*)d_out;                   // [8,30000]

  char* ws = (char*)d_ws;
  size_t off = 0;
  auto alloc = [&](size_t bytes) {
    char* p = ws + off;
    off += (bytes + 1023) & ~(size_t)1023;
    return p;
  };
  unsigned short* vocab_n = (unsigned short*)alloc(30000ull * 512 * 2);
  unsigned short* pt_n    = (unsigned short*)alloc(8192ull * 768 * 2);
  unsigned short* W1T     = (unsigned short*)alloc(768ull * 512 * 2);
  unsigned short* W2T     = (unsigned short*)alloc(768ull * 768 * 2);
  unsigned short* hbuf    = (unsigned short*)alloc(30000ull * 768 * 2);
  unsigned short* pbuf    = (unsigned short*)alloc(30000ull * 768 * 2);
  unsigned short* proto   = (unsigned short*)alloc(30208ull * 768 * 2);  // padded V
  float*          bnsums  = (float*)alloc(768ull * 2 * 4);
  float*          bnsc    = (float*)alloc(768ull * 4);
  float*          bnsh    = (float*)alloc(768ull * 4);
  unsigned*       maxkey  = (unsigned*)alloc(8ull * 30208 * 4);
  float*          partsum = (float*)alloc(8ull * 4);

  hipMemsetAsync(bnsums, 0, 768ull * 2 * 4, stream);
  hipMemsetAsync(maxkey, 0, 8ull * 30208 * 4, stream);
  hipMemsetAsync(proto + 30000ull * 768, 0, 208ull * 768 * 2, stream);
  hipMemsetAsync(partsum, 0, 8ull * 4, stream);

  transpose_kernel<<<CDIV(512 * 768, 256), 256, 0, stream>>>(W1, W1T, 512, 768);
  transpose_kernel<<<CDIV(768 * 768, 256), 256, 0, stream>>>(W2, W2T, 768, 768);
  rownorm_kernel<256, false><<<30000, 256, 0, stream>>>(vocab, vocab_n, 512);
  rownorm_kernel<256, false><<<8192, 256, 0, stream>>>(patch, pt_n, 768);

  // h = vocab_n @ W1 with fused BN-stats accumulation
  gemm_nt_kernel<0, true><<<dim3(6, 235), 256, 0, stream>>>(
      vocab_n, W1T, hbuf, nullptr, bnsums, 30000, 768, 512);
  bnfinal_kernel<<<3, 256, 0, stream>>>(bnsums, gamma, beta, bnsc, bnsh);
  bnapply_kernel<<<2048, 256, 0, stream>>>(hbuf, bnsc, bnsh);
  // p = h_bn @ W2 + b2
  gemm_nt_kernel<1, false><<<dim3(6, 235), 256, 0, stream>>>(
      hbuf, W2T, pbuf, b2, nullptr, 30000, 768, 768);
  rownorm_kernel<128, true><<<30000, 128, 0, stream>>>(pbuf, proto, 768);

  // big fused GEMM + max over patches
  gemm256_max_kernel<<<3776, 512, 0, stream>>>(pt_n, proto, maxkey);

  // softmax, fixed-shift two-pass
  smpart_kernel<<<dim3(30, 8), 256, 0, stream>>>(maxkey, partsum);
  smfinal_kernel<<<dim3(15, 8), 256, 0, stream>>>(maxkey, partsum, out);
}

// Round 5
// 592.058 us; speedup vs baseline: 1.5525x; 1.0733x over previous
//
#include <hip/hip_runtime.h>
#include <hip/hip_bf16.h>
#include <cstdint>

// patch_tokens [8,1024,768] f32, vocab [30000,512] f32, W1 [512,768], gamma/beta [768],
// W2 [768,768], b2 [768]  ->  out [8,30000] f32 (softmax mixture weights)

#define CDIV(a,b) (((a)+(b)-1)/(b))

using bf16x8 = __attribute__((ext_vector_type(8))) __bf16;
using f32x4  = __attribute__((ext_vector_type(4))) float;
using u16x8  = __attribute__((ext_vector_type(8))) unsigned short;
using u32x4  = __attribute__((ext_vector_type(4))) unsigned;

__device__ __forceinline__ unsigned short f2bf(float x) {
  unsigned u = __float_as_uint(x);
  u += 0x7fffu + ((u >> 16) & 1u);          // round-to-nearest-even
  return (unsigned short)(u >> 16);
}
__device__ __forceinline__ float bf2f(unsigned short b) {
  return __uint_as_float(((unsigned)b) << 16);
}
// order-preserving float<->uint key for atomicMax
__device__ __forceinline__ unsigned fkey(float x) {
  unsigned u = __float_as_uint(x);
  return (u & 0x80000000u) ? ~u : (u | 0x80000000u);
}
__device__ __forceinline__ float fdec(unsigned k) {
  unsigned u = (k & 0x80000000u) ? (k ^ 0x80000000u) : ~k;
  return __uint_as_float(u);
}

// ---------------------------------------------------------------------------
// Unified 8-phase 256x256 NT GEMM (T1+T2+T3+T4+T5), K = NT*64 compile-time.
// C[m][n] = sum_k A[m][k]*B[n][k].
// EPI 0: store bf16 C [M][NXT*256] + fused BN column stats (guard gm<=aclamp)
// EPI 1: store bf16 (C+bias) + fused per-row sumsq -> atomicAdd faux[row]
// EPI 2: per-column max over 256 rows, scaled by rnorm=faux[col], atomicMax maxk
// CPX != 0: bijective XCD swizzle with grid = 8*CPX.
// ---------------------------------------------------------------------------
template<int NT, int NXT, int EPI, int CPX>
__global__ __launch_bounds__(512, 1)
void gemm8p_kernel(const unsigned short* __restrict__ A,
                   const unsigned short* __restrict__ B,
                   unsigned short* __restrict__ Cout,
                   const float* __restrict__ bias,
                   float* __restrict__ faux,
                   unsigned* __restrict__ maxk,
                   int aclamp)
{
  constexpr int K = NT * 64;
  __shared__ __align__(16) unsigned short lds[8 * 8192];  // 128 KiB

  const int tid = threadIdx.x;
  const int w = tid >> 6, lane = tid & 63;
  const int lr = lane & 15, kg = lane >> 4;
  const int wr = w >> 2, wc = w & 3;          // 2 x 4 wave grid

  const int bid = blockIdx.x;
  const int wg = CPX ? ((bid & 7) * CPX + (bid >> 3)) : bid;
  const long m0 = (long)(wg / NXT) * 256;
  const long n0 = (long)(wg % NXT) * 256;

  auto stage = [&](int slot, int tk, int mat, int h) {
    const unsigned short* src = mat ? B : A;
    const long row0 = mat ? n0 : m0;
    unsigned short* dst = lds + (((slot * 2) + mat) * 2 + h) * 8192;
#pragma unroll
    for (int ld = 0; ld < 2; ++ld) {
      const int lc  = ld * 512 + tid;
      long row = row0 + (lc >> 2);
      if (!mat && row > aclamp) row = aclamp;       // clamp A source rows
      const int qc  = (lc & 3) ^ (((lc >> 2) >> 1) & 3);  // inverse-swizzled chunk
      const unsigned short* gp = src + row * K + tk * 64 + h * 32 + qc * 8;
      __builtin_amdgcn_global_load_lds(
          (const __attribute__((address_space(1))) void*)gp,
          (__attribute__((address_space(3))) void*)(dst + (ld * 512 + (w << 6)) * 8),
          16, 0, 0);
    }
  };
  auto rdA = [&](int s, int h, int fm) -> bf16x8 {
    const int row = wr * 128 + fm * 16 + lr;
    const int pc  = kg ^ ((row >> 1) & 3);
    return *(const bf16x8*)(lds + ((s * 2 + 0) * 2 + h) * 8192 + row * 32 + pc * 8);
  };
  auto rdB = [&](int s, int h, int fn) -> bf16x8 {
    const int row = wc * 64 + fn * 16 + lr;
    const int pc  = kg ^ ((row >> 1) & 3);
    return *(const bf16x8*)(lds + ((s * 2 + 1) * 2 + h) * 8192 + row * 32 + pc * 8);
  };

  f32x4 acc[8][4];
#pragma unroll
  for (int i = 0; i < 8; ++i)
#pragma unroll
    for (int j = 0; j < 4; ++j) acc[i][j] = f32x4{0.f, 0.f, 0.f, 0.f};

  stage(0, 0, 0, 0); stage(0, 0, 1, 0); stage(0, 0, 0, 1);
  stage(0, 0, 1, 1); stage(1, 1, 0, 0); stage(1, 1, 1, 0);
  asm volatile("s_waitcnt vmcnt(8)" ::: "memory");
  __builtin_amdgcn_s_barrier();

  bf16x8 a[4], b[4];
  auto tile_body = [&](int t, int s) {
    const int t1c = (t + 1 < NT) ? t + 1 : NT - 1;
    const int t2c = (t + 2 < NT) ? t + 2 : NT - 1;
    const int s1  = s ^ 1;

    // ---- P0: k-half 0, m-half 0 ----
#pragma unroll
    for (int i = 0; i < 4; ++i) a[i] = rdA(s, 0, i);
#pragma unroll
    for (int i = 0; i < 4; ++i) b[i] = rdB(s, 0, i);
    stage(s1, t1c, 0, 1);
    __builtin_amdgcn_s_barrier();
    asm volatile("s_waitcnt lgkmcnt(0)" ::: "memory");
    __builtin_amdgcn_sched_barrier(0);
    __builtin_amdgcn_s_setprio(1);
#pragma unroll
    for (int fm = 0; fm < 4; ++fm)
#pragma unroll
      for (int fn = 0; fn < 4; ++fn)
        acc[fm][fn] = __builtin_amdgcn_mfma_f32_16x16x32_bf16(a[fm], b[fn], acc[fm][fn], 0, 0, 0);
    __builtin_amdgcn_s_setprio(0);
    __builtin_amdgcn_sched_barrier(0);
    __builtin_amdgcn_s_barrier();

    // ---- P1: k-half 0, m-half 1 ----
#pragma unroll
    for (int i = 0; i < 4; ++i) a[i] = rdA(s, 0, 4 + i);
    stage(s1, t1c, 1, 1);
    __builtin_amdgcn_s_barrier();
    asm volatile("s_waitcnt lgkmcnt(0)" ::: "memory");
    __builtin_amdgcn_sched_barrier(0);
    __builtin_amdgcn_s_setprio(1);
#pragma unroll
    for (int fm = 0; fm < 4; ++fm)
#pragma unroll
      for (int fn = 0; fn < 4; ++fn)
        acc[4 + fm][fn] = __builtin_amdgcn_mfma_f32_16x16x32_bf16(a[fm], b[fn], acc[4 + fm][fn], 0, 0, 0);
    __builtin_amdgcn_s_setprio(0);
    asm volatile("s_waitcnt vmcnt(8)" ::: "memory");
    __builtin_amdgcn_sched_barrier(0);
    __builtin_amdgcn_s_barrier();

    // ---- P2: k-half 1, m-half 0 ----
#pragma unroll
    for (int i = 0; i < 4; ++i) a[i] = rdA(s, 1, i);
#pragma unroll
    for (int i = 0; i < 4; ++i) b[i] = rdB(s, 1, i);
    stage(s, t2c, 0, 0);
    __builtin_amdgcn_s_barrier();
    asm volatile("s_waitcnt lgkmcnt(0)" ::: "memory");
    __builtin_amdgcn_sched_barrier(0);
    __builtin_amdgcn_s_setprio(1);
#pragma unroll
    for (int fm = 0; fm < 4; ++fm)
#pragma unroll
      for (int fn = 0; fn < 4; ++fn)
        acc[fm][fn] = __builtin_amdgcn_mfma_f32_16x16x32_bf16(a[fm], b[fn], acc[fm][fn], 0, 0, 0);
    __builtin_amdgcn_s_setprio(0);
    __builtin_amdgcn_sched_barrier(0);
    __builtin_amdgcn_s_barrier();

    // ---- P3: k-half 1, m-half 1 ----
#pragma unroll
    for (int i = 0; i < 4; ++i) a[i] = rdA(s, 1, 4 + i);
    stage(s, t2c, 1, 0);
    __builtin_amdgcn_s_barrier();
    asm volatile("s_waitcnt lgkmcnt(0)" ::: "memory");
    __builtin_amdgcn_sched_barrier(0);
    __builtin_amdgcn_s_setprio(1);
#pragma unroll
    for (int fm = 0; fm < 4; ++fm)
#pragma unroll
      for (int fn = 0; fn < 4; ++fn)
        acc[4 + fm][fn] = __builtin_amdgcn_mfma_f32_16x16x32_bf16(a[fm], b[fn], acc[4 + fm][fn], 0, 0, 0);
    __builtin_amdgcn_s_setprio(0);
    asm volatile("s_waitcnt vmcnt(8)" ::: "memory");
    __builtin_amdgcn_sched_barrier(0);
    __builtin_amdgcn_s_barrier();
  };

  for (int tt = 0; tt < NT; tt += 2) { tile_body(tt, 0); tile_body(tt + 1, 1); }

  if (EPI == 2) {
    // column max over 256 rows, scale by rnorm, atomicMax into [8][30208]
    const int bb = (int)(m0 >> 10);
#pragma unroll
    for (int fn = 0; fn < 4; ++fn) {
      float mx = acc[0][fn][0];
#pragma unroll
      for (int fm = 0; fm < 8; ++fm)
#pragma unroll
        for (int j = 0; j < 4; ++j) mx = fmaxf(mx, acc[fm][fn][j]);
      mx = fmaxf(mx, __shfl_xor(mx, 16));
      mx = fmaxf(mx, __shfl_xor(mx, 32));
      const long gn = n0 + wc * 64 + fn * 16 + lr;
      if (lane < 16)
        atomicMax(maxk + (long)bb * 30208 + gn, fkey(mx * faux[gn]));
    }
  } else if (EPI == 0) {
    // store C, then fused BN column stats (sum, sumsq) with row guard
#pragma unroll
    for (int fm = 0; fm < 8; ++fm) {
      const long gmb = m0 + wr * 128 + fm * 16 + kg * 4;
#pragma unroll
      for (int fn = 0; fn < 4; ++fn) {
        const long gn = n0 + wc * 64 + fn * 16 + lr;
#pragma unroll
        for (int j = 0; j < 4; ++j)
          Cout[(gmb + j) * (NXT * 256) + gn] = f2bf(acc[fm][fn][j]);
      }
    }
#pragma unroll
    for (int fn = 0; fn < 4; ++fn) {
      const long gn = n0 + wc * 64 + fn * 16 + lr;
      float s = 0.f, q = 0.f;
#pragma unroll
      for (int fm = 0; fm < 8; ++fm) {
        const long gmb = m0 + wr * 128 + fm * 16 + kg * 4;
#pragma unroll
        for (int j = 0; j < 4; ++j) {
          if (gmb + j <= aclamp) {
            const float x = acc[fm][fn][j];
            s += x; q += x * x;
          }
        }
      }
      s += __shfl_xor(s, 16); s += __shfl_xor(s, 32);
      q += __shfl_xor(q, 16); q += __shfl_xor(q, 32);
      if (lane < 16) {
        atomicAdd(faux + gn, s);
        atomicAdd(faux + 768 + gn, q);
      }
    }
  } else {  // EPI == 1
    // store C+bias and fused per-row sumsq
    float bv[4];
#pragma unroll
    for (int fn = 0; fn < 4; ++fn) bv[fn] = bias[n0 + wc * 64 + fn * 16 + lr];
#pragma unroll
    for (int fm = 0; fm < 8; ++fm) {
      const long gmb = m0 + wr * 128 + fm * 16 + kg * 4;
#pragma unroll
      for (int j = 0; j < 4; ++j) {
        const long gm = gmb + j;
        float rs = 0.f;
#pragma unroll
        for (int fn = 0; fn < 4; ++fn) {
          const long gn = n0 + wc * 64 + fn * 16 + lr;
          const float x = acc[fm][fn][j] + bv[fn];
          Cout[gm * (NXT * 256) + gn] = f2bf(x);
          rs += x * x;
        }
        rs += __shfl_xor(rs, 1); rs += __shfl_xor(rs, 2);
        rs += __shfl_xor(rs, 4); rs += __shfl_xor(rs, 8);
        if (lr == 0) atomicAdd(faux + gm, rs);
      }
    }
  }
}

// ---------------------------------------------------------------------------
// Row L2-normalize, fully vectorized (one chunk per thread).
// ---------------------------------------------------------------------------
template<int BLOCK>
__global__ __launch_bounds__(BLOCK)
void rownorm_kernel(const float* __restrict__ in, unsigned short* __restrict__ out,
                    int cols)
{
  __shared__ float red[BLOCK / 64];
  const int row = blockIdx.x, tid = threadIdx.x;
  const int nch = cols / 4;

  float x[4];
  float ss = 0.f;
  if (tid < nch) {
    const f32x4 v = ((const f32x4*)(in + (size_t)row * cols))[tid];
#pragma unroll
    for (int j = 0; j < 4; ++j) { x[j] = v[j]; ss += x[j] * x[j]; }
  }
#pragma unroll
  for (int m = 32; m; m >>= 1) ss += __shfl_xor(ss, m);
  if ((tid & 63) == 0) red[tid >> 6] = ss;
  __syncthreads();
  float tot = 0.f;
#pragma unroll
  for (int i = 0; i < BLOCK / 64; ++i) tot += red[i];
  const float inv = 1.0f / fmaxf(sqrtf(tot), 1e-12f);

  if (tid < nch) {
    __attribute__((ext_vector_type(4))) unsigned short o;
#pragma unroll
    for (int j = 0; j < 4; ++j) o[j] = f2bf(x[j] * inv);
    ((decltype(o)*)(out + (size_t)row * cols))[tid] = o;
  }
}

// Both weight transposes in one launch: W1 [512][768]->W1T [768][512], W2 [768][768]->W2T
__global__ __launch_bounds__(256)
void transpose2_kernel(const float* __restrict__ W1, const float* __restrict__ W2,
                       unsigned short* __restrict__ W1T, unsigned short* __restrict__ W2T)
{
  const int i = blockIdx.x * 256 + threadIdx.x;
  if (i < 512 * 768) {
    const int r = i / 768, c = i - r * 768;
    W1T[c * 512 + r] = f2bf(W1[i]);
  } else {
    const int k = i - 512 * 768;
    if (k < 768 * 768) {
      const int r = k / 768, c = k - r * 768;
      W2T[c * 768 + r] = f2bf(W2[k]);
    }
  }
}

// scale/shift from accumulated sums
__global__ __launch_bounds__(256)
void bnfinal_kernel(const float* __restrict__ sums, const float* __restrict__ gamma,
                    const float* __restrict__ beta, float* __restrict__ sc,
                    float* __restrict__ sh)
{
  const int ch = blockIdx.x * 256 + threadIdx.x;
  if (ch < 768) {
    const float invV = 1.0f / 30000.0f;
    const float mean = sums[ch] * invV;
    const float var  = sums[768 + ch] * invV - mean * mean;
    const float s    = gamma[ch] / sqrtf(var + 1e-5f);
    sc[ch] = s;
    sh[ch] = beta[ch] - mean * s;
  }
}

// In-place BN + ReLU, short8-vectorized (30000 x 96 chunks of 8)
__global__ __launch_bounds__(256)
void bnapply_kernel(unsigned short* __restrict__ h, const float* __restrict__ sc,
                    const float* __restrict__ sh)
{
  const int total = 30000 * 96;
  for (int c = blockIdx.x * 256 + threadIdx.x; c < total; c += 2048 * 256) {
    const int ch = (c % 96) * 8;
    const u16x8 v = ((const u16x8*)h)[c];
    u16x8 o;
#pragma unroll
    for (int j = 0; j < 8; ++j) {
      const float y = fmaf(bf2f(v[j]), sc[ch + j], sh[ch + j]);
      o[j] = f2bf(fmaxf(y, 0.0f));
    }
    ((u16x8*)h)[c] = o;
  }
}

// rnorm[v] = 1/clamp(sqrt(rowsumsq[v]))
__global__ __launch_bounds__(256)
void rfin_kernel(const float* __restrict__ rsum, float* __restrict__ rnorm)
{
  const int v = blockIdx.x * 256 + threadIdx.x;
  if (v < 30208) rnorm[v] = 1.0f / fmaxf(sqrtf(rsum[v]), 1e-12f);
}

// Softmax with fixed shift (logits in [-1,1]): S = exp((l-1)*5)
__global__ __launch_bounds__(256)
void smpart_kernel(const unsigned* __restrict__ mk, float* __restrict__ partsum)
{
  __shared__ float red[4];
  const int b = blockIdx.y;
  const unsigned* row = mk + (size_t)b * 30208 + blockIdx.x * 1000;
  float s = 0.f;
  for (int t = threadIdx.x; t < 1000; t += 256)
    s += expf((fdec(row[t]) - 1.0f) * 5.0f);
#pragma unroll
  for (int m = 32; m; m >>= 1) s += __shfl_xor(s, m);
  if ((threadIdx.x & 63) == 0) red[threadIdx.x >> 6] = s;
  __syncthreads();
  if (threadIdx.x == 0)
    atomicAdd(partsum + b, red[0] + red[1] + red[2] + red[3]);
}

__global__ __launch_bounds__(256)
void smfinal_kernel(const unsigned* __restrict__ mk, const float* __restrict__ partsum,
                    float* __restrict__ out)
{
  const int b = blockIdx.y;
  const int c = blockIdx.x * 256 + threadIdx.x;
  if (c < 3750) {
    const unsigned* row = mk + (size_t)b * 30208 + c * 8;
    const float inv = 1.0f / partsum[b];
    const u32x4 k0 = *(const u32x4*)row;
    const u32x4 k1 = *(const u32x4*)(row + 4);
    f32x4 o0, o1;
#pragma unroll
    for (int j = 0; j < 4; ++j) {
      o0[j] = expf((fdec(k0[j]) - 1.0f) * 5.0f) * inv;
      o1[j] = expf((fdec(k1[j]) - 1.0f) * 5.0f) * inv;
    }
    float* op = out + (size_t)b * 30000 + c * 8;
    *(f32x4*)op = o0;
    *(f32x4*)(op + 4) = o1;
  }
}

extern "C" void kernel_launch(void* const* d_in, const int* in_sizes, int n_in,
                              void* d_out, int out_size, void* d_ws, size_t ws_size,
                              hipStream_t stream)
{
  (void)in_sizes; (void)n_in; (void)out_size; (void)ws_size;
  const float* patch = (const float*)d_in[0];   // [8,1024,768]
  const float* vocab = (const float*)d_in[1];   // [30000,512]
  const float* W1    = (const float*)d_in[2];   // [512,768]
  const float* gamma = (const float*)d_in[3];   // [768]
  const float* beta  = (const float*)d_in[4];   // [768]
  const float* W2    = (const float*)d_in[5];   // [768,768]
  const float* b2    = (const float*)d_in[6];   // [768]
  float* out = (float*)d_out;                   // [8,30000]

  char* ws = (char*)d_ws;
  size_t off = 0;
  auto alloc = [&](size_t bytes) {
    char* p = ws + off;
    off += (bytes + 1023) & ~(size_t)1023;
    return p;
  };
  unsigned short* vocab_n = (unsigned short*)alloc(30000ull * 512 * 2);
  unsigned short* pt_n    = (unsigned short*)alloc(8192ull * 768 * 2);
  unsigned short* W1T     = (unsigned short*)alloc(768ull * 512 * 2);
  unsigned short* W2T     = (unsigned short*)alloc(768ull * 768 * 2);
  unsigned short* hbuf    = (unsigned short*)alloc(30208ull * 768 * 2);  // padded M
  unsigned short* pbuf    = (unsigned short*)alloc(30208ull * 768 * 2);  // padded M
  // contiguous zeroed region: bnsums(1536) | rsum(30208) | partsum(8) | maxkey(8*30208)
  float* zbase = (float*)alloc((1536ull + 30208 + 8 + 8ull * 30208) * 4);
  float*    bnsums  = zbase;
  float*    rsum    = zbase + 1536;
  float*    partsum = zbase + 1536 + 30208;
  unsigned* maxkey  = (unsigned*)(zbase + 1536 + 30208 + 8);
  float*    bnsc    = (float*)alloc(768ull * 4);
  float*    bnsh    = (float*)alloc(768ull * 4);
  float*    rnorm   = (float*)alloc(30208ull * 4);

  hipMemsetAsync(zbase, 0, (1536ull + 30208 + 8 + 8ull * 30208) * 4, stream);

  transpose2_kernel<<<CDIV(512 * 768 + 768 * 768, 256), 256, 0, stream>>>(W1, W2, W1T, W2T);
  rownorm_kernel<256><<<30000, 256, 0, stream>>>(vocab, vocab_n, 512);
  rownorm_kernel<256><<<8192, 256, 0, stream>>>(patch, pt_n, 768);

  // h = vocab_n @ W1 (K=512) with fused BN stats; M padded to 30208
  gemm8p_kernel<8, 3, 0, 0><<<354, 512, 0, stream>>>(
      vocab_n, W1T, hbuf, nullptr, bnsums, nullptr, 29999);
  bnfinal_kernel<<<3, 256, 0, stream>>>(bnsums, gamma, beta, bnsc, bnsh);
  bnapply_kernel<<<2048, 256, 0, stream>>>(hbuf, bnsc, bnsh);

  // p = h_bn @ W2 + b2 (K=768) with fused per-row sumsq
  gemm8p_kernel<12, 3, 1, 0><<<354, 512, 0, stream>>>(
      hbuf, W2T, pbuf, b2, rsum, nullptr, 30207);
  rfin_kernel<<<118, 256, 0, stream>>>(rsum, rnorm);

  // logits+max over patches, normalization folded in via rnorm (scale>0 commutes with max)
  gemm8p_kernel<12, 118, 2, 472><<<3776, 512, 0, stream>>>(
      pt_n, pbuf, nullptr, nullptr, rnorm, maxkey, 8191);

  smpart_kernel<<<dim3(30, 8), 256, 0, stream>>>(maxkey, partsum);
  smfinal_kernel<<<dim3(15, 8), 256, 0, stream>>>(maxkey, partsum, out);
}